// Round 11
// baseline (149.885 us; speedup 1.0000x reference)
//
#include <hip/hip_runtime.h>
#include <stdint.h>

// ---------------- problem constants ----------------
#define B_SZ 8192
#define LOG8 2.0794415416798357f   // -log(1/8)
#define NCHUNKS 544                // sum_bi ceil((128-2bi)/8), 128x64 tiles bj>=2bi
#define NBLK 512

typedef __attribute__((ext_vector_type(8))) short short8;
typedef __attribute__((ext_vector_type(4))) float floatx4;

typedef __attribute__((address_space(1))) const uint4 guint4;
typedef __attribute__((address_space(3))) uint4 luint4;

__device__ inline void async_cp16(const uint4* g, uint4* l) {
    __builtin_amdgcn_global_load_lds((guint4*)g, (luint4*)l, 16, 0, 0);
}

__device__ inline unsigned short f2bf(float f) {
    unsigned int u = __float_as_uint(f);
    u = (u + 0x7FFFu + ((u >> 16) & 1u)) >> 16;   // RNE
    return (unsigned short)u;
}
__device__ inline float bf2f(unsigned short s) {
    return __uint_as_float(((unsigned int)s) << 16);
}
__device__ inline float wredf(float x) {
#pragma unroll
    for (int o = 32; o; o >>= 1) x += __shfl_down(x, o);
    return x;
}
__device__ inline int wredi(int x) {
#pragma unroll
    for (int o = 32; o; o >>= 1) x += __shfl_down(x, o);
    return x;
}

// ws layout:
//  nrm      bf16[8192*128]   @ 0
//  nlq      bf16[8192*8]     @ 2097152
//  pb       bf16[8192*8]     @ 2228224
//  aprime   f32[8192]        @ 2359296
//  klslot   f32[512]         @ 2392064
//  cntslot  u32[512]         @ 2394112
//  prepcol  f32[11*512]      @ 2396160   (column-major: [k*512 + block])
//  ctrl     u32[4]           @ 2418688   (0: prep barrier, 1: work, 2: done)

// ---------------- single fused persistent kernel ----------------
// 512 blocks x 512 thr, 64 KB LDS -> exactly 2 blocks/CU, all co-resident.
// Phase A: block b preps emb rows [16b,16b+16) (wave per row, 2/wave) and
//   routing rows [16b,16b+16) (thread per row); partials to prepcol.
// Grid barrier (ctrl[0]).
// Phase B: work-steal chunks (ctrl[1]); chunk = (bi, c): A panel 128 rows,
//   up to 8 128x64 B-strips, B double-buffered via global_load_lds (R10 body).
// Done (ctrl[2]): last block finalizes with all 512 threads.
__global__ __launch_bounds__(512, 4) void fused_all(
    const float* __restrict__ logits,
    const int* __restrict__ targets,
    const float* __restrict__ routing,
    const float* __restrict__ emb,
    const float* __restrict__ temp,
    unsigned short* __restrict__ nrm,
    unsigned short* __restrict__ nlq,
    unsigned short* __restrict__ pb,
    float* __restrict__ aprime,
    float* __restrict__ klslot,
    unsigned int* __restrict__ cntslot,
    float* __restrict__ prepcol,
    unsigned int* __restrict__ ctrl,
    float* __restrict__ out) {
    __shared__ uint4 sh[4096];   // A: [0..2047], B0: [2048..3071], B1: [3072..4095]
    __shared__ int msgSh;

    const int t = threadIdx.x;
    const int lane = t & 63, wave = t >> 6;
    const int bid = blockIdx.x;

    // ================= Phase A: prep =================
    // emb normalize -> bf16: 2 rows per wave
#pragma unroll
    for (int i = 0; i < 2; ++i) {
        int row = (bid << 4) + (wave << 1) + i;
        const float2* e2 = (const float2*)(emb + (size_t)row * 128);
        float2 v = e2[lane];
        float ss = v.x * v.x + v.y * v.y;
        ss = wredf(ss);
        ss = __shfl(ss, 0);
        float inv = rsqrtf(ss);
        ushort2 o;
        o.x = f2bf(v.x * inv);
        o.y = f2bf(v.y * inv);
        ((ushort2*)(nrm + (size_t)row * 128))[lane] = o;
    }

    // routing prep: one row per thread, threads 0..15
    float acc11[11];
#pragma unroll
    for (int k = 0; k < 11; ++k) acc11[k] = 0.f;
    if (t < 16) {
        int row = (bid << 4) + t;
        const float4* r4 = (const float4*)(routing + (size_t)row * 8);
        float4 va = r4[0], vb = r4[1];
        float v[8] = {va.x, va.y, va.z, va.w, vb.x, vb.y, vb.z, vb.w};

        float mx = v[0];
#pragma unroll
        for (int e = 1; e < 8; ++e) mx = fmaxf(mx, v[e]);
        float ex[8], s = 0.f;
#pragma unroll
        for (int e = 0; e < 8; ++e) { ex[e] = expf(v[e] - mx); s += ex[e]; }
        float ls = logf(s);
        float inv_s = 1.f / s;

        union { unsigned short u[8]; uint4 q; } lu, pu;
        float ap = 0.f;
#pragma unroll
        for (int e = 0; e < 8; ++e) {
            unsigned short pe = f2bf(ex[e] * inv_s);
            unsigned short le = f2bf(v[e] - mx - ls + LOG8);
            pu.u[e] = pe;
            lu.u[e] = le ^ 0x8000;         // store -lq (exact sign flip)
            ap += bf2f(pe) * bf2f(le);
        }
        ((uint4*)nlq)[row] = lu.q;
        ((uint4*)pb)[row] = pu.q;
        aprime[row] = ap;

        float eff = 0.f, ent = 0.f;
#pragma unroll
        for (int e = 0; e < 8; ++e) {
            if (v[e] < 0.1f) eff += v[e];
            ent += v[e] * logf(v[e] + 1e-8f);
            acc11[3 + e] = v[e];
        }

        const float* lg = logits + (size_t)row * 3;
        float a0 = lg[0], a1 = lg[1], a2 = lg[2];
        float mm = fmaxf(a0, fmaxf(a1, a2));
        float lse = mm + logf(expf(a0 - mm) + expf(a1 - mm) + expf(a2 - mm));
        int tg = targets[row];
        float tv = (tg == 0) ? a0 : ((tg == 1) ? a1 : a2);
        acc11[0] = lse - tv;
        acc11[1] = eff;
        acc11[2] = ent;
    }
    if (wave == 0) {
#pragma unroll
        for (int k = 0; k < 11; ++k) acc11[k] = wredf(acc11[k]);
        if (lane == 0) {
#pragma unroll
            for (int k = 0; k < 11; ++k) prepcol[k * NBLK + bid] = acc11[k];
        }
    }

    // ================= grid barrier =================
    __syncthreads();
    if (t == 0) {
        __threadfence();
        atomicAdd(&ctrl[0], 1u);
        while (__hip_atomic_load(&ctrl[0], __ATOMIC_ACQUIRE,
                                 __HIP_MEMORY_SCOPE_AGENT) < NBLK) {}
    }
    __syncthreads();

    // ================= Phase B: work-stealing tile chunks =================
    const uint4* n4 = (const uint4*)nrm;
    const int wr = wave >> 2, wc = wave & 3;   // 2 x 4 wave grid
    const int m = lane & 15, q = lane >> 4;
    const short8 zero8 = (short8){0, 0, 0, 0, 0, 0, 0, 0};

    float klLocal = 0.f;
    int cntLocal = 0;

#pragma unroll 1
    for (;;) {
        if (t == 0) msgSh = (int)atomicAdd(&ctrl[1], 1u);
        __syncthreads();
        const int chunk = msgSh;
        if (chunk >= NCHUNKS) break;

        // decode chunk -> (bi, c)
        int bi = 0, rem = chunk;
        for (;;) {
            int nc = (135 - 2 * bi) >> 3;  // ceil((128-2bi)/8)
            if (rem < nc) break;
            rem -= nc;
            ++bi;
        }
        const int bj0 = 2 * bi + (rem << 3);
        const int nt = min(8, 128 - bj0);
        const int iBase = bi << 7;

        // stage A panel (32 KB)
#pragma unroll
        for (int it = 0; it < 4; ++it) {
            int idx = t + (it << 9);
            int row = idx >> 4, s = idx & 15;
            int g = s ^ (row & 15);
            async_cp16(&n4[((size_t)(iBase + row) << 4) + g],
                       sh + (it << 9) + (wave << 6));
        }
        // stage B0 (16 KB)
        {
            const int jB = bj0 << 6;
#pragma unroll
            for (int it = 0; it < 2; ++it) {
                int idx = t + (it << 9);
                int row = idx >> 4, s = idx & 15;
                int g = s ^ (row & 15);
                async_cp16(&n4[((size_t)(jB + row) << 4) + g],
                           sh + 2048 + (it << 9) + (wave << 6));
            }
        }

        // hoisted A-side cross fragments (non-strip form)
        short8 crA[4];
#pragma unroll
        for (int a = 0; a < 4; ++a) {
            int ri = iBase + (wr << 6) + (a << 4) + m;
            short8 v = zero8;
            if (q == 0) v = *(const short8*)&nlq[(size_t)ri << 3];
            else if (q == 1) v = *(const short8*)&pb[(size_t)ri << 3];
            else if (q == 2) {
                v[0] = (short)f2bf(aprime[ri]);
                v[1] = (short)0x3F80;
            }
            crA[a] = v;
        }

        __syncthreads();               // drains A + B0

#pragma unroll 1
        for (int tt = 0; tt < nt; ++tt) {
            const int bj = bj0 + tt;
            const int jBase = bj << 6;
            const bool strip = ((bj >> 1) == bi);
            const int cur = 2048 + ((tt & 1) << 10);

            // prefetch next B strip (async, no regs)
            if (tt + 1 < nt) {
                const int jN = (bj + 1) << 6;
                const int nxt = 2048 + (((tt + 1) & 1) << 10);
#pragma unroll
                for (int it = 0; it < 2; ++it) {
                    int idx = t + (it << 9);
                    int row = idx >> 4, s = idx & 15;
                    int g = s ^ (row & 15);
                    async_cp16(&n4[((size_t)(jN + row) << 4) + g],
                               sh + nxt + (it << 9) + (wave << 6));
                }
            }

            // B-side cross fragment
            short8 crB;
            {
                int cj = jBase + (wc << 4) + m;
                short8 v = zero8;
                if (q == 0) v = *(const short8*)&pb[(size_t)cj << 3];
                else if (q == 1) v = *(const short8*)&nlq[(size_t)cj << 3];
                else if (q == 2) {
                    v[0] = (short)0x3F80;
                    v[1] = (short)f2bf(aprime[cj]);
                }
                crB = v;
            }

            // sim = A . B^T over K=128
            floatx4 simacc[4];
#pragma unroll
            for (int a = 0; a < 4; ++a) simacc[a] = (floatx4){0.f, 0.f, 0.f, 0.f};
#pragma unroll
            for (int ks = 0; ks < 4; ++ks) {
                const int gk = (ks << 2) + q;
                short8 bfr;
                {
                    int rb = (wc << 4) + m;
                    bfr = *(const short8*)(sh + cur + (rb << 4) + (gk ^ m));
                }
                short8 af[4];
#pragma unroll
                for (int a = 0; a < 4; ++a) {
                    int row = (wr << 6) + (a << 4) + m;
                    af[a] = *(const short8*)(sh + (row << 4) + (gk ^ m));
                }
#pragma unroll
                for (int a = 0; a < 4; ++a)
                    simacc[a] = __builtin_amdgcn_mfma_f32_16x16x32_bf16(
                        af[a], bfr, simacc[a], 0, 0, 0);
            }

            // epilogue
            const int gCol = jBase + (wc << 4) + m;
#pragma unroll
            for (int a = 0; a < 4; ++a) {
                short8 ca = crA[a];
                if (strip) {
                    if (q == 1) ca = zero8;
                    else if (q == 2) ca[0] = 0;
                }
                floatx4 cr = __builtin_amdgcn_mfma_f32_16x16x32_bf16(
                    ca, crB, (floatx4){0.f, 0.f, 0.f, 0.f}, 0, 0, 0);
                const int gRow0 = iBase + (wr << 6) + (a << 4) + (q << 2);
                if (strip) {
#pragma unroll
                    for (int r = 0; r < 4; ++r) {
                        if ((simacc[a][r] > 0.8f) && (gRow0 + r != gCol)) {
                            klLocal += cr[r];
                            cntLocal += 1;
                        }
                    }
                } else {
#pragma unroll
                    for (int r = 0; r < 4; ++r) {
                        if (simacc[a][r] > 0.8f) {
                            klLocal += cr[r];
                            cntLocal += 2;
                        }
                    }
                }
            }

            __syncthreads();           // drains B(t+1); guards buffer reuse
        }
    }

    // ================= block reduce + done counter =================
    klLocal = wredf(klLocal);
    cntLocal = wredi(cntLocal);
    float* redk = (float*)sh;
    int* redc = (int*)(redk + 8);
    if (lane == 0) { redk[wave] = klLocal; redc[wave] = cntLocal; }
    __syncthreads();
    if (t == 0) {
        float k = 0.f;
        int c = 0;
#pragma unroll
        for (int w = 0; w < 8; ++w) { k += redk[w]; c += redc[w]; }
        klslot[bid] = k;
        cntslot[bid] = (unsigned int)c;
        __threadfence();
        unsigned int old = atomicAdd(&ctrl[2], 1u);
        msgSh = (old == NBLK - 1);
    }
    __syncthreads();

    // ================= last block: finalize =================
    if (msgSh) {
        float k = __hip_atomic_load(&klslot[t], __ATOMIC_RELAXED,
                                    __HIP_MEMORY_SCOPE_AGENT);
        int c = (int)__hip_atomic_load(&cntslot[t], __ATOMIC_RELAXED,
                                       __HIP_MEMORY_SCOPE_AGENT);
        float pv[11];
#pragma unroll
        for (int kk = 0; kk < 11; ++kk)
            pv[kk] = __hip_atomic_load(&prepcol[kk * NBLK + t], __ATOMIC_RELAXED,
                                       __HIP_MEMORY_SCOPE_AGENT);
        k = wredf(k);
        c = wredi(c);
#pragma unroll
        for (int kk = 0; kk < 11; ++kk) pv[kk] = wredf(pv[kk]);

        float* rk = (float*)sh;                  // [8]
        int* rc = (int*)(rk + 8);                // [8]
        float* rp = (float*)(rc + 8);            // [8][11]
        if (lane == 0) {
            rk[wave] = k;
            rc[wave] = c;
#pragma unroll
            for (int kk = 0; kk < 11; ++kk) rp[wave * 11 + kk] = pv[kk];
        }
        __syncthreads();
        if (t == 0) {
            float K = 0.f;
            int C = 0;
            float sp[11];
#pragma unroll
            for (int kk = 0; kk < 11; ++kk) sp[kk] = 0.f;
#pragma unroll
            for (int w = 0; w < 8; ++w) {
                K += rk[w];
                C += rc[w];
#pragma unroll
                for (int kk = 0; kk < 11; ++kk) sp[kk] += rp[w * 11 + kk];
            }
            const float invB = 1.f / (float)B_SZ;
            float task = sp[0] * invB;
            float eff = 0.05f * sp[1] * invB;
            float entl = 0.01f * sp[2] * invB;
            float cons = 0.1f * (C > 0 ? K / (float)C : 0.f);
            float u[8], mean = 0.f;
            for (int e = 0; e < 8; ++e) { u[e] = sp[3 + e] * invB; mean += u[e]; }
            mean *= 0.125f;
            float var = 0.f;
            for (int e = 0; e < 8; ++e) { float d = u[e] - mean; var += d * d; }
            var *= (1.f / 7.f);            // unbiased (ddof=1)
            float lb = 0.1f * var * 64.f;  // * E^2
            float tt = temp[0] - 1.f;
            out[0] = task + lb + eff + cons + entl + 0.01f * tt * tt;
        }
    }
}

// ---------------- launch ----------------
extern "C" void kernel_launch(void* const* d_in, const int* in_sizes, int n_in,
                              void* d_out, int out_size, void* d_ws, size_t ws_size,
                              hipStream_t stream) {
    const float* logits = (const float*)d_in[0];
    const int* targets = (const int*)d_in[1];
    const float* routing = (const float*)d_in[2];
    const float* emb = (const float*)d_in[3];
    const float* temp = (const float*)d_in[4];

    char* ws = (char*)d_ws;
    unsigned short* nrm = (unsigned short*)ws;
    unsigned short* nlq = (unsigned short*)(ws + 2097152);
    unsigned short* pb = (unsigned short*)(ws + 2228224);
    float* aprime = (float*)(ws + 2359296);
    float* klslot = (float*)(ws + 2392064);
    unsigned int* cntslot = (unsigned int*)(ws + 2394112);
    float* prepcol = (float*)(ws + 2396160);
    unsigned int* ctrl = (unsigned int*)(ws + 2418688);

    hipMemsetAsync(ctrl, 0, 16, stream);
    fused_all<<<NBLK, 512, 0, stream>>>(logits, targets, routing, emb, temp,
                                        nrm, nlq, pb, aprime, klslot, cntslot,
                                        prepcol, ctrl, (float*)d_out);
}

// Round 12
// 103.671 us; speedup vs baseline: 1.4458x; 1.4458x over previous
//
#include <hip/hip_runtime.h>
#include <stdint.h>

// ---------------- problem constants ----------------
#define B_SZ 8192
#define LOG8 2.0794415416798357f   // -log(1/8)
#define NTILE 2080                 // 64*65/2 upper-triangular 128x128 tiles

typedef __attribute__((ext_vector_type(8))) short short8;
typedef __attribute__((ext_vector_type(4))) float floatx4;

typedef __attribute__((address_space(1))) const uint4 guint4;
typedef __attribute__((address_space(3))) uint4 luint4;

// async global->LDS 16B copy: per-lane global addr, wave-uniform LDS base,
// HW scatters lane l to base + l*16.
__device__ inline void async_cp16(const uint4* g, uint4* l) {
    __builtin_amdgcn_global_load_lds((guint4*)g, (luint4*)l, 16, 0, 0);
}

__device__ inline unsigned short f2bf(float f) {
    unsigned int u = __float_as_uint(f);
    u = (u + 0x7FFFu + ((u >> 16) & 1u)) >> 16;   // RNE
    return (unsigned short)u;
}
__device__ inline float bf2f(unsigned short s) {
    return __uint_as_float(((unsigned int)s) << 16);
}
__device__ inline float wredf(float x) {
#pragma unroll
    for (int o = 32; o; o >>= 1) x += __shfl_down(x, o);
    return x;
}
__device__ inline int wredi(int x) {
#pragma unroll
    for (int o = 32; o; o >>= 1) x += __shfl_down(x, o);
    return x;
}

// ws layout:
//  nrm      bf16[8192*128]   @ 0        (2097152 B)
//  nlq      bf16[8192*8]     @ 2097152  (-(logp+log8), sign-flipped bf16)
//  pb       bf16[8192*8]     @ 2228224
//  aprime   f32[8192]        @ 2359296
//  klslot   f32[2080]        @ 2392064  (per-block, non-atomic)
//  cntslot  u32[2080]        @ 2400384
//  prepslot f32[16*11]       @ 2408704

// ---------------- fused prep (272 blocks x 512) ----------------
__global__ __launch_bounds__(512) void prep_all(
    const float* __restrict__ logits,
    const int* __restrict__ targets,
    const float* __restrict__ routing,
    const float* __restrict__ emb,
    unsigned short* __restrict__ nrm,
    unsigned short* __restrict__ nlq,
    unsigned short* __restrict__ pb,
    float* __restrict__ aprime,
    float* __restrict__ prepslot) {
    __shared__ float pred[8][11];
    const int bid = blockIdx.x;
    const int lane = threadIdx.x & 63;
    const int wave = threadIdx.x >> 6;

    if (bid < 256) {
#pragma unroll
        for (int iter = 0; iter < 4; ++iter) {
            int row = (((iter << 8) + bid) << 3) + wave;
            const float2* e2 = (const float2*)(emb + (size_t)row * 128);
            float2 v = e2[lane];
            float ss = v.x * v.x + v.y * v.y;
            ss = wredf(ss);
            ss = __shfl(ss, 0);
            float inv = rsqrtf(ss);
            ushort2 o;
            o.x = f2bf(v.x * inv);
            o.y = f2bf(v.y * inv);
            ((ushort2*)(nrm + (size_t)row * 128))[lane] = o;
        }
        return;
    }

    int row = ((bid - 256) << 9) + threadIdx.x;

    const float4* r4 = (const float4*)(routing + (size_t)row * 8);
    float4 va = r4[0], vb = r4[1];
    float v[8] = {va.x, va.y, va.z, va.w, vb.x, vb.y, vb.z, vb.w};

    float mx = v[0];
#pragma unroll
    for (int e = 1; e < 8; ++e) mx = fmaxf(mx, v[e]);
    float ex[8], s = 0.f;
#pragma unroll
    for (int e = 0; e < 8; ++e) { ex[e] = expf(v[e] - mx); s += ex[e]; }
    float ls = logf(s);
    float inv_s = 1.f / s;

    union { unsigned short u[8]; uint4 q; } lu, pu;
    float ap = 0.f;
#pragma unroll
    for (int e = 0; e < 8; ++e) {
        unsigned short pe = f2bf(ex[e] * inv_s);
        unsigned short le = f2bf(v[e] - mx - ls + LOG8);
        pu.u[e] = pe;
        lu.u[e] = le ^ 0x8000;             // store -lq (exact sign flip)
        ap += bf2f(pe) * bf2f(le);
    }
    ((uint4*)nlq)[row] = lu.q;
    ((uint4*)pb)[row] = pu.q;
    aprime[row] = ap;

    float eff = 0.f, ent = 0.f;
#pragma unroll
    for (int e = 0; e < 8; ++e) {
        if (v[e] < 0.1f) eff += v[e];
        ent += v[e] * logf(v[e] + 1e-8f);
    }

    const float* lg = logits + (size_t)row * 3;
    float a0 = lg[0], a1 = lg[1], a2 = lg[2];
    float mm = fmaxf(a0, fmaxf(a1, a2));
    float lse = mm + logf(expf(a0 - mm) + expf(a1 - mm) + expf(a2 - mm));
    int tg = targets[row];
    float tv = (tg == 0) ? a0 : ((tg == 1) ? a1 : a2);
    float task = lse - tv;

    task = wredf(task);
    eff = wredf(eff);
    ent = wredf(ent);
    float cs[8];
#pragma unroll
    for (int e = 0; e < 8; ++e) cs[e] = wredf(v[e]);

    if (lane == 0) {
        pred[wave][0] = task;
        pred[wave][1] = eff;
        pred[wave][2] = ent;
#pragma unroll
        for (int e = 0; e < 8; ++e) pred[wave][3 + e] = cs[e];
    }
    __syncthreads();
    if (threadIdx.x < 11) {
        float s2 = 0.f;
#pragma unroll
        for (int w = 0; w < 8; ++w) s2 += pred[w][threadIdx.x];
        prepslot[(bid - 256) * 11 + threadIdx.x] = s2;
    }
}

// ---------------- main: symmetric fused sim-mask + KL ----------------
// 128x128 upper-tri tiles; 512 thr (8 waves 2x4); 48 KB LDS -> 3 blocks/CU.
// 3-plane split-K via global_load_lds (XOR swizzle on global granule):
//   P0=A[k0..63], P1=B[k0..63], P2=A[k64..127]; B[k64..127] reuses P0.
//   issue A0,B0 -> sync -> issue A1 -> compute K0/1 -> sync ->
//   issue B1(P0) -> sync -> compute K2/3. Plane slot (row*8+s) holds global
//   granule chunk*8 + (s ^ (row&7)).
__global__ __launch_bounds__(512, 4) void tile_sym(
    const unsigned short* __restrict__ nrm,
    const unsigned short* __restrict__ nlq,
    const unsigned short* __restrict__ pb,
    const float* __restrict__ aprime,
    float* __restrict__ klslot,
    unsigned int* __restrict__ cntslot) {
    __shared__ uint4 sh[3072];   // 48 KB: P0[0..1023] P1[1024..2047] P2[2048..3071]

    const int t = threadIdx.x;
    const int L = blockIdx.x;
    const int wave = t >> 6, lane = t & 63;

    // triangular decode: bi <= bj
    int bi = (int)((129.0f - sqrtf((float)(16641 - 8 * L))) * 0.5f);
    int T = bi * 64 - ((bi * (bi - 1)) >> 1);
    while (L < T) { --bi; T = bi * 64 - ((bi * (bi - 1)) >> 1); }
    while (L >= T + (64 - bi)) { T += 64 - bi; ++bi; }
    const int bj = bi + (L - T);
    const bool diag = (bi == bj);
    const int iBase = bi << 7, jBase = bj << 7;

    const uint4* n4 = (const uint4*)nrm;
    // staging slot for this thread (plane-local): 2 issues x 512
    const int r0 = t >> 3, s0 = t & 7;
    const int r1 = (t + 512) >> 3, s1 = (t + 512) & 7;
    const int g0 = s0 ^ (r0 & 7), g1 = s1 ^ (r1 & 7);

    // ---- issue A0 (P0) and B0 (P1): k columns 0..63 ----
    async_cp16(&n4[((size_t)(iBase + r0) << 4) + g0], sh + (wave << 6));
    async_cp16(&n4[((size_t)(iBase + r1) << 4) + g1], sh + 512 + (wave << 6));
    async_cp16(&n4[((size_t)(jBase + r0) << 4) + g0], sh + 1024 + (wave << 6));
    async_cp16(&n4[((size_t)(jBase + r1) << 4) + g1], sh + 1536 + (wave << 6));

    __syncthreads();                   // sync1: A0,B0 resident

    // ---- issue A1 (P2): k columns 64..127 ----
    async_cp16(&n4[((size_t)(iBase + r0) << 4) + 8 + g0], sh + 2048 + (wave << 6));
    async_cp16(&n4[((size_t)(iBase + r1) << 4) + 8 + g1], sh + 2560 + (wave << 6));

    const int wr = wave >> 2, wc = wave & 3;   // 2 x 4 wave grid
    const int m = lane & 15, q = lane >> 4;
    const int m7 = m & 7;
    const short8 zero8 = (short8){0, 0, 0, 0, 0, 0, 0, 0};

    // cross fragments (overlap A1 flight):
    //  A: q0 = -lq_i, q1 = p_i (0 on diag), q2: k16=bf16(ap_i)(0 on diag), k17=1
    //  B: q0 = p_j,   q1 = -lq_j,           q2: k16=1, k17=bf16(ap_j)
    short8 crA[4], crB[2];
#pragma unroll
    for (int a = 0; a < 4; ++a) {
        int ri = iBase + (wr << 6) + (a << 4) + m;
        short8 v = zero8;
        if (q == 0) v = *(const short8*)&nlq[(size_t)ri << 3];
        else if (q == 1) { if (!diag) v = *(const short8*)&pb[(size_t)ri << 3]; }
        else if (q == 2) {
            v[1] = (short)0x3F80;
            if (!diag) v[0] = (short)f2bf(aprime[ri]);
        }
        crA[a] = v;
    }
#pragma unroll
    for (int b = 0; b < 2; ++b) {
        int cj = jBase + (wc << 5) + (b << 4) + m;
        short8 v = zero8;
        if (q == 0) v = *(const short8*)&pb[(size_t)cj << 3];
        else if (q == 1) v = *(const short8*)&nlq[(size_t)cj << 3];
        else if (q == 2) {
            v[0] = (short)0x3F80;
            v[1] = (short)f2bf(aprime[cj]);
        }
        crB[b] = v;
    }

    floatx4 simacc[4][2];
#pragma unroll
    for (int a = 0; a < 4; ++a)
#pragma unroll
        for (int b = 0; b < 2; ++b) simacc[a][b] = (floatx4){0.f, 0.f, 0.f, 0.f};

    const int raOff = (wr << 6) << 3;              // A row base * 8 slots
    const int rbOff = (wc << 5) << 3;              // B row base * 8 slots

    // ---- compute K0/1 from P0 (A0) x P1 (B0) ----
#pragma unroll
    for (int ks = 0; ks < 2; ++ks) {
        const int sg = ((ks << 2) + q) ^ m7;
        short8 af[4], bfr[2];
#pragma unroll
        for (int a = 0; a < 4; ++a)
            af[a] = *(const short8*)(sh + raOff + (((a << 4) + m) << 3) + sg);
#pragma unroll
        for (int b = 0; b < 2; ++b)
            bfr[b] = *(const short8*)(sh + 1024 + rbOff + (((b << 4) + m) << 3) + sg);
#pragma unroll
        for (int a = 0; a < 4; ++a)
#pragma unroll
            for (int b = 0; b < 2; ++b)
                simacc[a][b] = __builtin_amdgcn_mfma_f32_16x16x32_bf16(
                    af[a], bfr[b], simacc[a][b], 0, 0, 0);
    }

    __syncthreads();                   // sync2: P0/P1 free; A1 drained

    // ---- issue B1 into P0: k columns 64..127 ----
    async_cp16(&n4[((size_t)(jBase + r0) << 4) + 8 + g0], sh + (wave << 6));
    async_cp16(&n4[((size_t)(jBase + r1) << 4) + 8 + g1], sh + 512 + (wave << 6));

    __syncthreads();                   // sync3: B1 resident

    // ---- compute K2/3 from P2 (A1) x P0 (B1) ----
#pragma unroll
    for (int ks = 0; ks < 2; ++ks) {
        const int sg = ((ks << 2) + q) ^ m7;
        short8 af[4], bfr[2];
#pragma unroll
        for (int a = 0; a < 4; ++a)
            af[a] = *(const short8*)(sh + 2048 + raOff + (((a << 4) + m) << 3) + sg);
#pragma unroll
        for (int b = 0; b < 2; ++b)
            bfr[b] = *(const short8*)(sh + rbOff + (((b << 4) + m) << 3) + sg);
#pragma unroll
        for (int a = 0; a < 4; ++a)
#pragma unroll
            for (int b = 0; b < 2; ++b)
                simacc[a][b] = __builtin_amdgcn_mfma_f32_16x16x32_bf16(
                    af[a], bfr[b], simacc[a][b], 0, 0, 0);
    }

    // ---- epilogue: kl via one MFMA per C-tile, masked accumulate ----
    float klLocal = 0.f;
    int cntLocal = 0;
#pragma unroll
    for (int a = 0; a < 4; ++a) {
        const int gRow0 = iBase + (wr << 6) + (a << 4) + (q << 2);
#pragma unroll
        for (int b = 0; b < 2; ++b) {
            const int gCol = jBase + (wc << 5) + (b << 4) + m;
            floatx4 cr = __builtin_amdgcn_mfma_f32_16x16x32_bf16(
                crA[a], crB[b], (floatx4){0.f, 0.f, 0.f, 0.f}, 0, 0, 0);
            if (diag) {
#pragma unroll
                for (int r = 0; r < 4; ++r) {
                    if ((simacc[a][b][r] > 0.8f) && (gRow0 + r != gCol)) {
                        klLocal += cr[r];
                        cntLocal += 1;
                    }
                }
            } else {
#pragma unroll
                for (int r = 0; r < 4; ++r) {
                    if (simacc[a][b][r] > 0.8f) {
                        klLocal += cr[r];
                        cntLocal += 2;
                    }
                }
            }
        }
    }

    klLocal = wredf(klLocal);
    cntLocal = wredi(cntLocal);

    // reduction scratch in P1 (not read after sync2)
    float* redk = (float*)(sh + 1024);
    int* redc = (int*)(redk + 8);
    if (lane == 0) { redk[wave] = klLocal; redc[wave] = cntLocal; }
    __syncthreads();

    if (t == 0) {
        float k = 0.f;
        int c = 0;
#pragma unroll
        for (int w = 0; w < 8; ++w) { k += redk[w]; c += redc[w]; }
        klslot[L] = k;                     // unique slot: no atomic
        cntslot[L] = (unsigned int)c;
    }
}

// ---------------- finalize (1 block x 256) ----------------
__global__ void finalize_k(const float* __restrict__ klslot,
                           const unsigned int* __restrict__ cntslot,
                           const float* __restrict__ prepslot,
                           const float* __restrict__ temp,
                           float* __restrict__ out) {
    __shared__ float sk[4];
    __shared__ int sc[4];
    __shared__ float sp[11];
    const int t = threadIdx.x, lane = t & 63, wave = t >> 6;

    float k = 0.f;
    int c = 0;
    for (int i = t; i < NTILE; i += 256) { k += klslot[i]; c += (int)cntslot[i]; }
    k = wredf(k);
    c = wredi(c);
    if (lane == 0) { sk[wave] = k; sc[wave] = c; }
    if (t < 11) {
        float s = 0.f;
        for (int r = 0; r < 16; ++r) s += prepslot[r * 11 + t];
        sp[t] = s;
    }
    __syncthreads();
    if (t == 0) {
        float K = sk[0] + sk[1] + sk[2] + sk[3];
        int C = sc[0] + sc[1] + sc[2] + sc[3];
        const float invB = 1.f / (float)B_SZ;
        float task = sp[0] * invB;
        float eff = 0.05f * sp[1] * invB;
        float entl = 0.01f * sp[2] * invB;
        float cons = 0.1f * (C > 0 ? K / (float)C : 0.f);
        float u[8], mean = 0.f;
        for (int e = 0; e < 8; ++e) { u[e] = sp[3 + e] * invB; mean += u[e]; }
        mean *= 0.125f;
        float var = 0.f;
        for (int e = 0; e < 8; ++e) { float d = u[e] - mean; var += d * d; }
        var *= (1.f / 7.f);                // unbiased (ddof=1)
        float lb = 0.1f * var * 64.f;      // * E^2
        float tt = temp[0] - 1.f;
        out[0] = task + lb + eff + cons + entl + 0.01f * tt * tt;
    }
}

// ---------------- launch ----------------
extern "C" void kernel_launch(void* const* d_in, const int* in_sizes, int n_in,
                              void* d_out, int out_size, void* d_ws, size_t ws_size,
                              hipStream_t stream) {
    const float* logits = (const float*)d_in[0];
    const int* targets = (const int*)d_in[1];
    const float* routing = (const float*)d_in[2];
    const float* emb = (const float*)d_in[3];
    const float* temp = (const float*)d_in[4];

    char* ws = (char*)d_ws;
    unsigned short* nrm = (unsigned short*)ws;
    unsigned short* nlq = (unsigned short*)(ws + 2097152);
    unsigned short* pb = (unsigned short*)(ws + 2228224);
    float* aprime = (float*)(ws + 2359296);
    float* klslot = (float*)(ws + 2392064);
    unsigned int* cntslot = (unsigned int*)(ws + 2400384);
    float* prepslot = (float*)(ws + 2408704);

    prep_all<<<272, 512, 0, stream>>>(logits, targets, routing, emb,
                                      nrm, nlq, pb, aprime, prepslot);
    tile_sym<<<NTILE, 512, 0, stream>>>(nrm, nlq, pb, aprime, klslot, cntslot);
    finalize_k<<<1, 256, 0, stream>>>(klslot, cntslot, prepslot, temp,
                                      (float*)d_out);
}